// Round 1
// baseline (57.994 us; speedup 1.0000x reference)
//
#include <hip/hip_runtime.h>
#include <math.h>

#define N_BINS 64
#define EPS_W 0.001f

__device__ inline float wave_sum(float v) {
    #pragma unroll
    for (int off = 32; off >= 1; off >>= 1) v += __shfl_xor(v, off, 64);
    return v;
}
__device__ inline float wave_max(float v) {
    #pragma unroll
    for (int off = 32; off >= 1; off >>= 1) v = fmaxf(v, __shfl_xor(v, off, 64));
    return v;
}
__device__ inline float wave_scan_incl(float v, int lane) {
    #pragma unroll
    for (int off = 1; off < 64; off <<= 1) {
        float o = __shfl_up(v, off, 64);
        if (lane >= off) v += o;
    }
    return v;
}

__device__ inline float interp_one(float tp, const float* __restrict__ s_et,
                                   const float* __restrict__ s_eu) {
    // idx = largest j in [0,63] with e_t[j] <= tp  (== clip(count(e<=tp)-1, 0, 63)
    // because e_t[0]=0 <= tp and monotone edges make the >=64 case collapse to 63)
    int idx = 0;
    #pragma unroll
    for (int s = 32; s; s >>= 1) {
        int cand = idx + s;            // max 32+16+8+4+2+1 = 63
        idx = (s_et[cand] <= tp) ? cand : idx;
    }
    float et0 = s_et[idx];
    float et1 = s_et[idx + 1];
    float eu0 = s_eu[idx];
    float eu1 = s_eu[idx + 1];
    return eu0 + (eu1 - eu0) * ((tp - et0) / (et1 - et0));
}

__global__ __launch_bounds__(256) void losscdf_kernel(
    const float* __restrict__ t,
    const float* __restrict__ l_t,
    const float* __restrict__ l_u,
    float* __restrict__ out,
    int n)
{
    __shared__ float s_et[N_BINS + 1];
    __shared__ float s_eu[N_BINS + 1];

    // ---- per-block edge-table build (first wave only; 64 lanes == 64 bins) ----
    if (threadIdx.x < 64) {
        int lane = threadIdx.x;
        float lt = l_t[lane];
        float lu = l_u[lane];

        // w_t = softmax(l_t) + eps, renormalized
        float m  = wave_max(lt);
        float ex = expf(lt - m);
        float se = wave_sum(ex);
        float wt = ex / se + EPS_W;
        float swt = wave_sum(wt);
        wt = wt / swt;

        // w_u = exp(l_u) + eps, normalized (no max-subtraction, per reference)
        float eu = expf(lu) + EPS_W;
        float seu = wave_sum(eu);
        float wu = eu / seu;

        float ct = wave_scan_incl(wt, lane);
        float cu = wave_scan_incl(wu, lane);

        if (lane == 0) { s_et[0] = 0.0f; s_eu[0] = 0.0f; }
        s_et[lane + 1] = ct;
        s_eu[lane + 1] = cu;
    }
    __syncthreads();

    // ---- main loop: float4 grid-stride over t ----
    int n4 = n >> 2;
    const float4* __restrict__ t4 = (const float4*)t;
    float4* __restrict__ o4 = (float4*)out;
    int stride = gridDim.x * blockDim.x;
    for (int i = blockIdx.x * blockDim.x + threadIdx.x; i < n4; i += stride) {
        float4 v = t4[i];
        float4 r;
        r.x = interp_one(v.x, s_et, s_eu);
        r.y = interp_one(v.y, s_et, s_eu);
        r.z = interp_one(v.z, s_et, s_eu);
        r.w = interp_one(v.w, s_et, s_eu);
        o4[i] = r;
    }

    // scalar tail (n % 4 != 0 safety; n = 131072 here so this is dead)
    int tail = n & 3;
    if (tail && blockIdx.x == 0 && (int)threadIdx.x < tail) {
        int i = (n4 << 2) + threadIdx.x;
        out[i] = interp_one(t[i], s_et, s_eu);
    }
}

extern "C" void kernel_launch(void* const* d_in, const int* in_sizes, int n_in,
                              void* d_out, int out_size, void* d_ws, size_t ws_size,
                              hipStream_t stream) {
    const float* t   = (const float*)d_in[0];
    const float* l_t = (const float*)d_in[1];
    const float* l_u = (const float*)d_in[2];
    float* out = (float*)d_out;
    int n = in_sizes[0];                 // 32*4096 = 131072
    int n4 = n >> 2;                     // one float4 per thread
    int block = 256;
    int grid = (n4 + block - 1) / block; // 128 blocks
    if (grid < 1) grid = 1;
    losscdf_kernel<<<grid, block, 0, stream>>>(t, l_t, l_u, out, n);
}

// Round 2
// 57.919 us; speedup vs baseline: 1.0013x; 1.0013x over previous
//
#include <hip/hip_runtime.h>
#include <math.h>

#define N_BINS 64
#define EPS_W 0.001f
#define LUT_SIZE 256

__device__ inline float wave_sum(float v) {
    #pragma unroll
    for (int off = 32; off >= 1; off >>= 1) v += __shfl_xor(v, off, 64);
    return v;
}
__device__ inline float wave_max(float v) {
    #pragma unroll
    for (int off = 32; off >= 1; off >>= 1) v = fmaxf(v, __shfl_xor(v, off, 64));
    return v;
}
__device__ inline float wave_scan_incl(float v, int lane) {
    #pragma unroll
    for (int off = 1; off < 64; off <<= 1) {
        float o = __shfl_up(v, off, 64);
        if (lane >= off) v += o;
    }
    return v;
}

__global__ __launch_bounds__(256) void losscdf_kernel(
    const float* __restrict__ t,
    const float* __restrict__ l_t,
    const float* __restrict__ l_u,
    float* __restrict__ out,
    int n)
{
    __shared__ float  s_et[N_BINS + 1];       // e_t knots
    __shared__ float4 s_bin[N_BINS];          // {et0, eu0, slope, et1} per bin
    __shared__ int    s_lut[LUT_SIZE];        // floor(t*256) -> starting idx

    // ---- phase 1: edge tables (first wave; 64 lanes == 64 bins) ----
    if (threadIdx.x < 64) {
        int lane = threadIdx.x;
        float lt = l_t[lane];
        float lu = l_u[lane];

        // w_t = softmax(l_t) + eps, renormalized
        float m  = wave_max(lt);
        float ex = expf(lt - m);
        float se = wave_sum(ex);
        float wt = ex / se + EPS_W;
        float swt = wave_sum(wt);
        wt = wt / swt;

        // w_u = exp(l_u) + eps, normalized (no max-subtraction, per reference)
        float eu = expf(lu) + EPS_W;
        float seu = wave_sum(eu);
        float wu = eu / seu;

        float ct = wave_scan_incl(wt, lane);
        float cu = wave_scan_incl(wu, lane);

        // edges: e[0]=0, e[lane+1]=cumsum
        if (lane == 0) s_et[0] = 0.0f;
        s_et[lane + 1] = ct;

        // bin record needs eu0 = e_u[lane] = cu - wu, eu1 = cu,
        // et0 = e_t[lane] = ct - wt, et1 = ct
        float et0 = ct - wt;
        float et1 = ct;
        float eu0 = cu - wu;
        float eu1 = cu;
        // lane 0's et0/eu0 must be exactly 0 (cumsum identity holds but force it)
        if (lane == 0) { et0 = 0.0f; eu0 = 0.0f; }
        float4 b;
        b.x = et0;
        b.y = eu0;
        b.z = (eu1 - eu0) / (et1 - et0);
        b.w = et1;
        s_bin[lane] = b;
    }
    __syncthreads();

    // ---- phase 2: slot LUT (all 256 threads, one slot each) ----
    {
        float slot_lo = (float)threadIdx.x * (1.0f / LUT_SIZE);
        int idx = 0;
        #pragma unroll
        for (int s = 32; s; s >>= 1) {
            int cand = idx + s;               // max 63
            idx = (s_et[cand] <= slot_lo) ? cand : idx;
        }
        s_lut[threadIdx.x] = idx;
    }
    __syncthreads();

    // ---- phase 3: one element per thread (512 blocks -> 2 waves/SIMD) ----
    int i = blockIdx.x * blockDim.x + threadIdx.x;
    if (i < n) {
        float tp = t[i];
        // exact slot: *256 is a power-of-2 scale, no rounding across boundary
        int k = (int)(tp * (float)LUT_SIZE);
        k = min(max(k, 0), LUT_SIZE - 1);
        int idx = s_lut[k];
        // fix-up to exact bucket-search semantics: largest j<=63 with e_t[j]<=tp
        while (idx < N_BINS - 1 && s_et[idx + 1] <= tp) idx++;
        float4 b = s_bin[idx];
        out[i] = fmaf(b.z, tp - b.x, b.y);
    }
}

extern "C" void kernel_launch(void* const* d_in, const int* in_sizes, int n_in,
                              void* d_out, int out_size, void* d_ws, size_t ws_size,
                              hipStream_t stream) {
    const float* t   = (const float*)d_in[0];
    const float* l_t = (const float*)d_in[1];
    const float* l_u = (const float*)d_in[2];
    float* out = (float*)d_out;
    int n = in_sizes[0];                     // 32*4096 = 131072
    int block = 256;
    int grid = (n + block - 1) / block;      // 512 blocks
    if (grid < 1) grid = 1;
    losscdf_kernel<<<grid, block, 0, stream>>>(t, l_t, l_u, out, n);
}